// Round 6
// baseline (261.488 us; speedup 1.0000x reference)
//
#include <hip/hip_runtime.h>

// Butterfly (untied, increasing stride), batch=32768, n=1024, m=10 stages, nstack=1.
//
// Round-6: eliminate ALL __shfl_xor (384/wave, ~2800 DS-pipe cyc/wave -- the
// per-CU serialized bottleneck identified from r5's counters) via two
// wave-private LDS lane-transposes. Three data layouts, every stage intra-lane:
//   A (load):  lane holds e = 16*lane + j            -> stages 0..3 intra
//   E:         lane = {e[9:8], e[3:0]}, slot = e[7:4] -> stages 4..7 intra
//   F:         lane = e[7:2], slot = {e[9:8], e[1:0]} -> stages 8,9 intra,
//              dense float4 stores + bias
// Transpose buffer map addr(e) = e + 4*(e>>4) + 16*((e>>8)&3): b128 writes are
// uniform 8-accesses/bank (minimum), b32 reads <=2-way (free). No barriers, no
// block-level staging phase; twiddles are straight-line global float4 loads
// (L1-resident 8 KB/stage). LDS 21 KB/block, VGPR target <=128 ((256,2) cap,
// the proven regime) -> occupancy cap 16 waves/CU.
// r5 fallback: 97 us/dispatch, WRITE_SIZE exactly = output (no spill).

constexpr int N = 1024;
constexpr int B_ROWS = 4;   // rows per wave
constexpr int WAVES = 4;    // waves per block (block = 256 threads)
constexpr int WBUF  = 1344; // floats per wave transpose buffer (max idx 1323)

// ---- stage helpers: pair (lo,hi), twiddle float4 (t00,t01,t10,t11),
//      lo' = t00*lo + t01*hi ; hi' = t10*lo + t11*hi ; pr from e_low.

// Layout A: lane holds e = 16*lane + j (j = 0..15). Stages 0..3.
template<int ST>
__device__ __forceinline__ void stageA(float (&v)[4][16],
                                       const float4* __restrict__ tw4,
                                       const int lane)
{
    constexpr int s = 1 << ST;
    #pragma unroll
    for (int pi = 0; pi < 8; ++pi) {
        const int jl = ((pi >> ST) << (ST + 1)) | (pi & (s - 1));
        const int jh = jl + s;
        const int e  = 16 * lane + jl;
        const int pr = ((e >> (ST + 1)) << ST) | (e & (s - 1));
        const float4 t = tw4[ST * 512 + pr];
        #pragma unroll
        for (int r = 0; r < 4; ++r) {
            const float lo = v[r][jl], hi = v[r][jh];
            v[r][jl] = t.x * lo + t.y * hi;
            v[r][jh] = t.z * lo + t.w * hi;
        }
    }
}

// Layout E: lane (a=lane>>4, b=lane&15) holds e = 256*a + 16*k + b (k=0..15).
// Stages 4..7 (pair bit ST-4 of k).
template<int ST>
__device__ __forceinline__ void stageE(float (&v)[4][16],
                                       const float4* __restrict__ tw4,
                                       const int lane)
{
    constexpr int s  = 1 << ST;
    constexpr int km = 1 << (ST - 4);
    const int a = lane >> 4, b = lane & 15;
    #pragma unroll
    for (int pi = 0; pi < 8; ++pi) {
        const int kl = ((pi >> (ST - 4)) << (ST - 3)) | (pi & (km - 1));
        const int kh = kl + km;
        const int e  = 256 * a + 16 * kl + b;
        const int pr = ((e >> (ST + 1)) << ST) | (e & (s - 1));
        const float4 t = tw4[ST * 512 + pr];
        #pragma unroll
        for (int r = 0; r < 4; ++r) {
            const float lo = v[r][kl], hi = v[r][kh];
            v[r][kl] = t.x * lo + t.y * hi;
            v[r][kh] = t.z * lo + t.w * hi;
        }
    }
}

// Layout F: lane holds e = a*256 + 4*lane + b10, slot m = 4*a + b10.
// Stages 8,9 (pair bit ST-8 of a).
template<int ST>
__device__ __forceinline__ void stageF(float (&v)[4][16],
                                       const float4* __restrict__ tw4,
                                       const int lane)
{
    constexpr int s  = 1 << ST;
    constexpr int am = 1 << (ST - 8);
    #pragma unroll
    for (int pi = 0; pi < 8; ++pi) {
        const int ai   = pi >> 2;       // 0..1
        const int b10  = pi & 3;
        const int a_lo = ((ai >> (ST - 8)) << (ST - 7)) | (ai & (am - 1));
        const int a_hi = a_lo + am;
        const int ml   = a_lo * 4 + b10;
        const int mh   = a_hi * 4 + b10;
        const int e    = a_lo * 256 + 4 * lane + b10;
        const int pr   = ((e >> (ST + 1)) << ST) | (e & (s - 1));
        const float4 t = tw4[ST * 512 + pr];
        #pragma unroll
        for (int r = 0; r < 4; ++r) {
            const float lo = v[r][ml], hi = v[r][mh];
            v[r][ml] = t.x * lo + t.y * hi;
            v[r][mh] = t.z * lo + t.w * hi;
        }
    }
}

__global__ __launch_bounds__(256, 2)
void butterfly_kernel(const float* __restrict__ x,
                      const float* __restrict__ tw,    // [10][512][2][2]
                      const float* __restrict__ bias,  // [1024]
                      float* __restrict__ out)
{
    __shared__ __align__(16) float tl[WAVES][WBUF];    // 21504 B, wave-private

    const int t    = threadIdx.x;
    const int lane = t & 63;
    const int g    = t >> 6;
    float* wb = tl[g];

    const size_t row0 = ((size_t)blockIdx.x * WAVES + g) * B_ROWS;
    const float4* tw4 = (const float4*)tw;

    float v[4][16];

    // ---- load, layout A: lane reads its 64B run per row (lines fully used) ----
    #pragma unroll
    for (int r = 0; r < 4; ++r) {
        const float* px = x + (row0 + r) * N + 16 * lane;
        #pragma unroll
        for (int i = 0; i < 4; ++i) {
            const float4 d = *(const float4*)(px + 4 * i);
            v[r][4 * i + 0] = d.x; v[r][4 * i + 1] = d.y;
            v[r][4 * i + 2] = d.z; v[r][4 * i + 3] = d.w;
        }
    }

    // ---- stages 0..3 (layout A) ----
    stageA<0>(v, tw4, lane);
    stageA<1>(v, tw4, lane);
    stageA<2>(v, tw4, lane);
    stageA<3>(v, tw4, lane);

    // ---- transpose A -> E, per row through the wave-private buffer ----
    // addr(e) = e + 4*(e>>4) + 16*((e>>8)&3). Write: e = 16*lane + j (contig 16).
    // Read: e = 256*a + 16*k + b -> addr = 336*a + 20*k + b.
    {
        const int wbase = 20 * lane + 16 * ((lane >> 4) & 3);
        const int a = lane >> 4, b = lane & 15;
        const int rb = 336 * a + b;
        #pragma unroll
        for (int r = 0; r < 4; ++r) {
            #pragma unroll
            for (int i = 0; i < 4; ++i)
                *(float4*)(wb + wbase + 4 * i) =
                    make_float4(v[r][4 * i + 0], v[r][4 * i + 1],
                                v[r][4 * i + 2], v[r][4 * i + 3]);
            #pragma unroll
            for (int k = 0; k < 16; ++k)
                v[r][k] = wb[rb + 20 * k];
        }
    }

    // ---- stages 4..7 (layout E) ----
    stageE<4>(v, tw4, lane);
    stageE<5>(v, tw4, lane);
    stageE<6>(v, tw4, lane);
    stageE<7>(v, tw4, lane);

    // ---- transpose E -> F ----
    // u(e) = 256*e98 + 16*e30 + e74; addr2(u) = u + 4*(u>>4) + 16*((u>>8)&3).
    // Write (lane a,b holds k=0..15): addr2 = 336*a + 20*b + k (contig 16).
    // Read (lane L, slot m=4*aa+b10): addr2 = 336*aa + 80*(L&3) + 20*b10 + (L>>2).
    {
        const int a = lane >> 4, b = lane & 15;
        const int wbase = 336 * a + 20 * b;
        const int rb = 80 * (lane & 3) + (lane >> 2);
        #pragma unroll
        for (int r = 0; r < 4; ++r) {
            #pragma unroll
            for (int i = 0; i < 4; ++i)
                *(float4*)(wb + wbase + 4 * i) =
                    make_float4(v[r][4 * i + 0], v[r][4 * i + 1],
                                v[r][4 * i + 2], v[r][4 * i + 3]);
            #pragma unroll
            for (int m = 0; m < 16; ++m)
                v[r][m] = wb[rb + 336 * (m >> 2) + 20 * (m & 3)];
        }
    }

    // ---- stages 8,9 (layout F) ----
    stageF<8>(v, tw4, lane);
    stageF<9>(v, tw4, lane);

    // ---- store with bias, layout F: dense float4 per 256-float block ----
    #pragma unroll
    for (int r = 0; r < 4; ++r) {
        float* po = out + (row0 + r) * N + 4 * lane;
        #pragma unroll
        for (int aa = 0; aa < 4; ++aa) {
            const float4 bb = *(const float4*)(bias + aa * 256 + 4 * lane);
            float4 o;
            o.x = v[r][4 * aa + 0] + bb.x;
            o.y = v[r][4 * aa + 1] + bb.y;
            o.z = v[r][4 * aa + 2] + bb.z;
            o.w = v[r][4 * aa + 3] + bb.w;
            *(float4*)(po + aa * 256) = o;
        }
    }
}

extern "C" void kernel_launch(void* const* d_in, const int* in_sizes, int n_in,
                              void* d_out, int out_size, void* d_ws, size_t ws_size,
                              hipStream_t stream) {
    const float* x    = (const float*)d_in[0];   // [batch][1024]
    const float* tw   = (const float*)d_in[1];   // [1][10][512][2][2]
    const float* bias = (const float*)d_in[2];   // [1024]
    float* out        = (float*)d_out;

    const int batch  = in_sizes[0] / N;          // 32768
    const int blocks = batch / (B_ROWS * WAVES); // 2048
    hipLaunchKernelGGL(butterfly_kernel, dim3(blocks), dim3(256), 0, stream,
                       x, tw, bias, out);
}

// Round 7
// 246.200 us; speedup vs baseline: 1.0621x; 1.0621x over previous
//
#include <hip/hip_runtime.h>

// Butterfly (untied, increasing stride), batch=32768, n=1024, m=10 stages, nstack=1.
//
// Round-7 = r6's shuffle-free 3-layout structure + r5's block-level LDS twiddle
// staging, targeted at the gathers r6's counters exposed (VALUBusy 19.5->12.5%:
// 80 scattered twiddle gathers/wave became the latency bottleneck).
//  * Layouts: A (stages 0..3, lane holds e=16*lane+j) -> transpose -> E (4..7,
//    lane={e[9:8],e[3:0]}) -> transpose -> F (8,9, lane=e[7:2], dense stores).
//    All stages intra-lane; zero __shfl_xor.
//  * Twiddles for A (0..3) and F (8,9) pre-permuted into LDS once per block:
//    tbl[st][pi*64+lane] float4 -> lane-consecutive conflict-free ds_read_b128.
//    (These were the 64-line/gather stages.) E stages keep global gathers --
//    their pr is lane-consecutive in the low 4 bits (4x256B runs, 16 lines).
//  * Wave-private transpose buffers (21.5 KB) OVERLAY the A-tables after a
//    barrier (A-tables dead after stage 3) -> total LDS 48 KB.
//  * __launch_bounds__(256,2) (proven 128-VGPR regime, no spill).
// Fallbacks: r5 = 97us (LDS cross-twiddles + shuffles), r6 = 110us.

constexpr int N = 1024;
constexpr int B_ROWS = 4;   // rows per wave
constexpr int WAVES = 4;    // waves per block (block = 256 threads)
constexpr int WBUF  = 1344; // floats per wave transpose buffer (max idx 1323)

// ---- stage math: pair (lo,hi), twiddle float4 (t00,t01,t10,t11),
//      lo' = t00*lo + t01*hi ; hi' = t10*lo + t11*hi.

// Layout A: lane holds e = 16*lane + j (j=0..15). Stages 0..3. Twiddle from LDS.
template<int ST>
__device__ __forceinline__ void stageA(float (&v)[4][16],
                                       const float4* __restrict__ tbl, // LDS [512]
                                       const int lane)
{
    constexpr int s = 1 << ST;
    #pragma unroll
    for (int pi = 0; pi < 8; ++pi) {
        const int jl = ((pi >> ST) << (ST + 1)) | (pi & (s - 1));
        const int jh = jl + s;
        const float4 t = tbl[(pi << 6) | lane];
        #pragma unroll
        for (int r = 0; r < 4; ++r) {
            const float lo = v[r][jl], hi = v[r][jh];
            v[r][jl] = t.x * lo + t.y * hi;
            v[r][jh] = t.z * lo + t.w * hi;
        }
    }
}

// Layout E: lane (a=lane>>4, b=lane&15) holds e = 256*a + 16*k + b (k=0..15).
// Stages 4..7 (pair bit ST-4 of k). Twiddle from global (16-line gather).
template<int ST>
__device__ __forceinline__ void stageE(float (&v)[4][16],
                                       const float4* __restrict__ tw4,
                                       const int lane)
{
    constexpr int s  = 1 << ST;
    constexpr int km = 1 << (ST - 4);
    const int a = lane >> 4, b = lane & 15;
    #pragma unroll
    for (int pi = 0; pi < 8; ++pi) {
        const int kl = ((pi >> (ST - 4)) << (ST - 3)) | (pi & (km - 1));
        const int kh = kl + km;
        const int e  = 256 * a + 16 * kl + b;
        const int pr = ((e >> (ST + 1)) << ST) | (e & (s - 1));
        const float4 t = tw4[ST * 512 + pr];
        #pragma unroll
        for (int r = 0; r < 4; ++r) {
            const float lo = v[r][kl], hi = v[r][kh];
            v[r][kl] = t.x * lo + t.y * hi;
            v[r][kh] = t.z * lo + t.w * hi;
        }
    }
}

// Layout F: lane holds e = a*256 + 4*lane + b10, slot m = 4*a + b10.
// Stages 8,9 (pair bit ST-8 of a). Twiddle from LDS.
template<int ST>
__device__ __forceinline__ void stageF(float (&v)[4][16],
                                       const float4* __restrict__ tbl, // LDS [512]
                                       const int lane)
{
    constexpr int am = 1 << (ST - 8);
    #pragma unroll
    for (int pi = 0; pi < 8; ++pi) {
        const int ai   = pi >> 2;       // 0..1
        const int b10  = pi & 3;
        const int a_lo = ((ai >> (ST - 8)) << (ST - 7)) | (ai & (am - 1));
        const int a_hi = a_lo + am;
        const int ml   = a_lo * 4 + b10;
        const int mh   = a_hi * 4 + b10;
        const float4 t = tbl[(pi << 6) | lane];
        #pragma unroll
        for (int r = 0; r < 4; ++r) {
            const float lo = v[r][ml], hi = v[r][mh];
            v[r][ml] = t.x * lo + t.y * hi;
            v[r][mh] = t.z * lo + t.w * hi;
        }
    }
}

__global__ __launch_bounds__(256, 2)
void butterfly_kernel(const float* __restrict__ x,
                      const float* __restrict__ tw,    // [10][512][2][2]
                      const float* __restrict__ bias,  // [1024]
                      float* __restrict__ out)
{
    // 48 KB total. tblA is overlaid by the wave transpose buffers after stage 3.
    __shared__ __align__(16) float4 tblA[4][512];      // 32 KB, stages 0..3
    __shared__ __align__(16) float4 tblF[2][512];      // 16 KB, stages 8,9

    const int t    = threadIdx.x;
    const int lane = t & 63;
    const int g    = t >> 6;

    const float4* tw4 = (const float4*)tw;

    // ---- stage pre-permuted twiddle tables (once per block, all 256 threads) ----
    // tbl[st][pi*64+lane] = tw4[st*512 + pr(st,pi,lane)]
    #pragma unroll
    for (int st = 0; st < 4; ++st) {
        const int s = 1 << st;
        #pragma unroll
        for (int h = 0; h < 2; ++h) {
            const int idx = t + 256 * h;               // 0..511
            const int pi = idx >> 6, ln = idx & 63;
            const int jl = ((pi >> st) << (st + 1)) | (pi & (s - 1));
            const int e  = 16 * ln + jl;
            const int pr = ((e >> (st + 1)) << st) | (e & (s - 1));
            tblA[st][idx] = tw4[st * 512 + pr];
        }
    }
    #pragma unroll
    for (int f = 0; f < 2; ++f) {
        const int st = 8 + f;
        const int s  = 1 << st;
        const int am = 1 << (st - 8);
        #pragma unroll
        for (int h = 0; h < 2; ++h) {
            const int idx = t + 256 * h;
            const int pi = idx >> 6, ln = idx & 63;
            const int ai = pi >> 2, b10 = pi & 3;
            const int a_lo = ((ai >> (st - 8)) << (st - 7)) | (ai & (am - 1));
            const int e  = a_lo * 256 + 4 * ln + b10;
            const int pr = ((e >> (st + 1)) << st) | (e & (s - 1));
            tblF[f][idx] = tw4[st * 512 + pr];
        }
    }
    __syncthreads();

    const size_t row0 = ((size_t)blockIdx.x * WAVES + g) * B_ROWS;

    float v[4][16];

    // ---- load, layout A: lane reads its 64B run per row ----
    #pragma unroll
    for (int r = 0; r < 4; ++r) {
        const float* px = x + (row0 + r) * N + 16 * lane;
        #pragma unroll
        for (int i = 0; i < 4; ++i) {
            const float4 d = *(const float4*)(px + 4 * i);
            v[r][4 * i + 0] = d.x; v[r][4 * i + 1] = d.y;
            v[r][4 * i + 2] = d.z; v[r][4 * i + 3] = d.w;
        }
    }

    // ---- stages 0..3 (layout A, LDS twiddles) ----
    stageA<0>(v, tblA[0], lane);
    stageA<1>(v, tblA[1], lane);
    stageA<2>(v, tblA[2], lane);
    stageA<3>(v, tblA[3], lane);

    __syncthreads();   // all waves done with tblA -> safe to overlay
    float* wb = reinterpret_cast<float*>(tblA) + g * WBUF;  // wave-private 5.25 KB

    // ---- transpose A -> E ----
    // addr(e) = e + 4*(e>>4) + 16*((e>>8)&3). Write: e = 16*lane + j (contig 16).
    // Read: e = 256*a + 16*k + b -> addr = 336*a + 20*k + b.
    {
        const int wbase = 20 * lane + 16 * ((lane >> 4) & 3);
        const int a = lane >> 4, b = lane & 15;
        const int rb = 336 * a + b;
        #pragma unroll
        for (int r = 0; r < 4; ++r) {
            #pragma unroll
            for (int i = 0; i < 4; ++i)
                *(float4*)(wb + wbase + 4 * i) =
                    make_float4(v[r][4 * i + 0], v[r][4 * i + 1],
                                v[r][4 * i + 2], v[r][4 * i + 3]);
            #pragma unroll
            for (int k = 0; k < 16; ++k)
                v[r][k] = wb[rb + 20 * k];
        }
    }

    // ---- stages 4..7 (layout E, global twiddles: lane-consecutive low bits) ----
    stageE<4>(v, tw4, lane);
    stageE<5>(v, tw4, lane);
    stageE<6>(v, tw4, lane);
    stageE<7>(v, tw4, lane);

    // ---- transpose E -> F ----
    // u(e) = 256*e98 + 16*e30 + e74; addr2(u) = u + 4*(u>>4) + 16*((u>>8)&3).
    // Write (lane a,b holds k): addr2 = 336*a + 20*b + k (contig 16).
    // Read (lane L, slot m=4*aa+b10): addr2 = 336*aa + 80*(L&3) + 20*b10 + (L>>2).
    {
        const int a = lane >> 4, b = lane & 15;
        const int wbase = 336 * a + 20 * b;
        const int rb = 80 * (lane & 3) + (lane >> 2);
        #pragma unroll
        for (int r = 0; r < 4; ++r) {
            #pragma unroll
            for (int i = 0; i < 4; ++i)
                *(float4*)(wb + wbase + 4 * i) =
                    make_float4(v[r][4 * i + 0], v[r][4 * i + 1],
                                v[r][4 * i + 2], v[r][4 * i + 3]);
            #pragma unroll
            for (int m = 0; m < 16; ++m)
                v[r][m] = wb[rb + 336 * (m >> 2) + 20 * (m & 3)];
        }
    }

    // ---- stages 8,9 (layout F, LDS twiddles) ----
    stageF<8>(v, tblF[0], lane);
    stageF<9>(v, tblF[1], lane);

    // ---- store with bias, layout F: dense float4 per 256-float block ----
    float4 bb[4];
    #pragma unroll
    for (int aa = 0; aa < 4; ++aa)
        bb[aa] = *(const float4*)(bias + aa * 256 + 4 * lane);
    #pragma unroll
    for (int r = 0; r < 4; ++r) {
        float* po = out + (row0 + r) * N + 4 * lane;
        #pragma unroll
        for (int aa = 0; aa < 4; ++aa) {
            float4 o;
            o.x = v[r][4 * aa + 0] + bb[aa].x;
            o.y = v[r][4 * aa + 1] + bb[aa].y;
            o.z = v[r][4 * aa + 2] + bb[aa].z;
            o.w = v[r][4 * aa + 3] + bb[aa].w;
            *(float4*)(po + aa * 256) = o;
        }
    }
}

extern "C" void kernel_launch(void* const* d_in, const int* in_sizes, int n_in,
                              void* d_out, int out_size, void* d_ws, size_t ws_size,
                              hipStream_t stream) {
    const float* x    = (const float*)d_in[0];   // [batch][1024]
    const float* tw   = (const float*)d_in[1];   // [1][10][512][2][2]
    const float* bias = (const float*)d_in[2];   // [1024]
    float* out        = (float*)d_out;

    const int batch  = in_sizes[0] / N;          // 32768
    const int blocks = batch / (B_ROWS * WAVES); // 2048
    hipLaunchKernelGGL(butterfly_kernel, dim3(blocks), dim3(256), 0, stream,
                       x, tw, bias, out);
}